// Round 7
// baseline (331.008 us; speedup 1.0000x reference)
//
#include <hip/hip_runtime.h>
#include <math.h>

#define N_   128
#define H_   400
#define W_   400
#define MS_  28
#define CT_  80
#define CS_  53
#define HW_  (H_*W_)
#define NCH_ (CS_ + N_)   // 181
#define WG_  1600
#define IGN_ 255
#define G_   8            // channel groups
#define CPG_ 23           // ceil(181/8)
#define PPT_ 4            // pixels per thread (float4)
#define BT_  256          // threads per block
#define PPB_ (BT_*PPT_)   // 1024 pixels per block
#define GX_  ((HW_ + PPB_ - 1)/PPB_)   // 157

struct NParam {
  int vy_lo, vy_hi, vx_lo, vx_hi;   // mask-valid box (inclusive)
  int cy1, cy2, cx1, cx2;           // sem box (y in [cy1,cy2), x in [cx1,cx2))
  float sy, sx;                     // 28/hh, 28/ww
  int y0b, x0b;                     // floor(bbox/4)
  int mlbase, thbase;               // offsets into mask_logits / thing_logit
  int pad0, pad1;                   // 64 B
};

// Device globals (BSS = zeroed at module load). Invariant: all counters are
// zero at kernel entry and restored to zero by the blocks that consume them,
// so every (graph-replayed) launch sees identical state. No d_ws use.
__device__ float        g_acc[2];
__device__ unsigned int g_done;
__device__ unsigned int g_tick[GX_];
__device__ float        g_pm[G_*HW_];   // partial LSE max per (group, pixel)
__device__ float        g_ps[G_*HW_];   // partial LSE sum

__device__ __forceinline__ void lse_update(float v, float& m, float& s) {
  float d = v - m;
  float e = __expf(-fabsf(d));
  s = (d > 0.0f) ? fmaf(s, e, 1.0f) : (s + e);
  m = fmaxf(m, v);
}

// blockIdx.x = pixel tile (1024 px), blockIdx.y = channel group.
// Phase 1: compute this group's channels + partial LSE for the tile.
// Last group-block per tile (ticket) performs phase 2 (combine + NLL) with
// partials L2-hot; the globally-last tile-reducer writes the loss.
__global__ __launch_bounds__(256) void fused_kernel(
    const float* __restrict__ mask_logits,
    const float* __restrict__ stuff_logit,
    const float* __restrict__ thing_logit,
    const float* __restrict__ bbox,
    const int*   __restrict__ cls_idx,
    const int*   __restrict__ gt,
    float* out)
{
  __shared__ NParam spar[N_];
  __shared__ unsigned int stick;
  int tid = threadIdx.x;
  int bx  = blockIdx.x, grp = blockIdx.y;

  if (tid < N_) {
    int n = tid;
    float b0 = bbox[4*n+0]*0.25f, b1 = bbox[4*n+1]*0.25f,
          b2 = bbox[4*n+2]*0.25f, b3 = bbox[4*n+3]*0.25f;
    int x0b = (int)floorf(b0), y0b = (int)floorf(b1);
    int x2b = (int)floorf(b2), y2b = (int)floorf(b3);
    int hh = y2b - y0b + 1, ww = x2b - x0b + 1;
    NParam p;
    p.vy_lo = max(y0b, 0); p.vy_hi = min(y2b, H_-1);
    p.vx_lo = max(x0b, 0); p.vx_hi = min(x2b, W_-1);
    p.cy1 = (int)b1; p.cx1 = (int)b0;                 // trunc (positive)
    p.cy2 = (int)(rintf(b3) + 1.0f);                  // jnp.round = RNE
    p.cx2 = (int)(rintf(b2) + 1.0f);
    p.sy = 28.0f / (float)hh; p.sx = 28.0f / (float)ww;
    p.y0b = y0b; p.x0b = x0b;
    int cls = cls_idx[n];
    p.mlbase = (n*CT_ + cls)*(MS_*MS_);
    p.thbase = cls*HW_;
    p.pad0 = 0; p.pad1 = 0;
    spar[n] = p;
  }
  __syncthreads();

  int pix0 = (bx*BT_ + tid)*PPT_;
  bool act = (pix0 < HW_);
  int y = 0, xb = 0;
  if (act) { y = pix0 / W_; xb = pix0 - y*W_; }   // W_%4==0: shared y

  int c0 = grp*CPG_;
  int c1 = min(NCH_, c0 + CPG_);

  if (act) {
    float mv[PPT_], sv[PPT_];
    #pragma unroll
    for (int k = 0; k < PPT_; ++k) { mv[k] = -INFINITY; sv[k] = 0.0f; }

    int c = c0;
    int cs_end = min(c1, CS_);
    for (; c < cs_end; ++c) {                     // stuff: float4 copy + lse
      float4 v = *(const float4*)(stuff_logit + c*HW_ + pix0);
      *(float4*)(out + c*HW_ + pix0) = v;
      lse_update(v.x, mv[0], sv[0]);
      lse_update(v.y, mv[1], sv[1]);
      lse_update(v.z, mv[2], sv[2]);
      lse_update(v.w, mv[3], sv[3]);
    }
    for (; c < c1; ++c) {                         // thing channels
      int n = c - CS_;
      NParam p = spar[n];
      float vv[PPT_] = {0.0f, 0.0f, 0.0f, 0.0f};
      if (y >= p.cy1 && y < p.cy2 && xb < p.cx2 && xb+PPT_-1 >= p.cx1) {
        float4 t = *(const float4*)(thing_logit + p.thbase + pix0);
        float tk[4] = {t.x, t.y, t.z, t.w};
        #pragma unroll
        for (int k = 0; k < PPT_; ++k) {
          int x = xb + k;
          if (x >= p.cx1 && x < p.cx2) vv[k] = tk[k];
        }
      }
      if (y >= p.vy_lo && y <= p.vy_hi && xb <= p.vx_hi && xb+PPT_-1 >= p.vx_lo) {
        float srcy = ((float)(y - p.y0b) + 0.5f)*p.sy - 0.5f;
        float fy = floorf(srcy); float ty = srcy - fy;
        int i0 = (int)fminf(fmaxf(fy,        0.0f), (float)(MS_-1));
        int i1 = (int)fminf(fmaxf(fy + 1.0f, 0.0f), (float)(MS_-1));
        const float* r0p = mask_logits + p.mlbase + i0*MS_;
        const float* r1p = mask_logits + p.mlbase + i1*MS_;
        #pragma unroll
        for (int k = 0; k < PPT_; ++k) {
          int x = xb + k;
          if (x >= p.vx_lo && x <= p.vx_hi) {
            float srcx = ((float)(x - p.x0b) + 0.5f)*p.sx - 0.5f;
            float fx = floorf(srcx); float tx = srcx - fx;
            int j0 = (int)fminf(fmaxf(fx,        0.0f), (float)(MS_-1));
            int j1 = (int)fminf(fmaxf(fx + 1.0f, 0.0f), (float)(MS_-1));
            float r0 = r0p[j0]*(1.0f - tx) + r0p[j1]*tx;
            float r1 = r1p[j0]*(1.0f - tx) + r1p[j1]*tx;
            vv[k] += r0*(1.0f - ty) + r1*ty;
          }
        }
      }
      *(float4*)(out + c*HW_ + pix0) = make_float4(vv[0], vv[1], vv[2], vv[3]);
      lse_update(vv[0], mv[0], sv[0]);
      lse_update(vv[1], mv[1], sv[1]);
      lse_update(vv[2], mv[2], sv[2]);
      lse_update(vv[3], mv[3], sv[3]);
    }

    *(float4*)(g_pm + grp*HW_ + pix0) = make_float4(mv[0], mv[1], mv[2], mv[3]);
    *(float4*)(g_ps + grp*HW_ + pix0) = make_float4(sv[0], sv[1], sv[2], sv[3]);
  }

  // ---- per-tile ticket: last of the G_ sibling blocks reduces this tile ----
  __syncthreads();                       // all block stores issued
  if (tid == 0) {
    __threadfence();                     // release: make our writes visible
    stick = atomicAdd(&g_tick[bx], 1u);
  }
  __syncthreads();
  if (stick != G_ - 1) return;

  __threadfence();                       // acquire: see siblings' writes
  float nll = 0.0f, cnt = 0.0f;
  if (act) {
    float4 m4 = *(const float4*)(g_pm + pix0);
    float4 s4 = *(const float4*)(g_ps + pix0);
    float mv[PPT_] = {m4.x, m4.y, m4.z, m4.w};
    float sv[PPT_] = {s4.x, s4.y, s4.z, s4.w};
    #pragma unroll
    for (int g = 1; g < G_; ++g) {
      float4 mg4 = *(const float4*)(g_pm + g*HW_ + pix0);
      float4 sg4 = *(const float4*)(g_ps + g*HW_ + pix0);
      float mg[PPT_] = {mg4.x, mg4.y, mg4.z, mg4.w};
      float sg[PPT_] = {sg4.x, sg4.y, sg4.z, sg4.w};
      #pragma unroll
      for (int k = 0; k < PPT_; ++k) {
        float M = fmaxf(mv[k], mg[k]);
        sv[k] = sv[k]*__expf(mv[k] - M) + sg[k]*__expf(mg[k] - M);
        mv[k] = M;
      }
    }
    #pragma unroll
    for (int k = 0; k < PPT_; ++k) {
      int g = gt[y*(4*WG_) + (xb + k)*4];     // gt_panoptic[4y, 4x]
      bool valid = (g != IGN_);
      int tc = min(max(g, 0), NCH_-1);
      float vt = out[tc*HW_ + pix0 + k];
      nll += valid ? (mv[k] + __logf(sv[k]) - vt) : 0.0f;
      cnt += valid ? 1.0f : 0.0f;
    }
  }

  for (int off = 32; off >= 1; off >>= 1) {
    nll += __shfl_down(nll, off, 64);
    cnt += __shfl_down(cnt, off, 64);
  }
  __shared__ float red[8];
  int lane = tid & 63, wid = tid >> 6;
  if (lane == 0) { red[wid*2] = nll; red[wid*2+1] = cnt; }
  __syncthreads();
  if (tid == 0) {
    float ts  = red[0] + red[2] + red[4] + red[6];
    float tcn = red[1] + red[3] + red[5] + red[7];
    atomicAdd(&g_acc[0], ts);
    atomicAdd(&g_acc[1], tcn);
    g_tick[bx] = 0;                      // restore invariant for next launch
    __threadfence();
    unsigned int d = atomicAdd(&g_done, 1u);
    if (d == GX_ - 1) {                  // globally last tile-reducer
      __threadfence();
      float loss = g_acc[0] / fmaxf(g_acc[1], 1.0f);   // LOSS_W = 1.0
      out[NCH_*HW_] = loss;
      g_acc[0] = 0.0f; g_acc[1] = 0.0f; g_done = 0u;   // restore invariant
    }
  }
}

extern "C" void kernel_launch(void* const* d_in, const int* in_sizes, int n_in,
                              void* d_out, int out_size, void* d_ws, size_t ws_size,
                              hipStream_t stream) {
  const float* mask_logits = (const float*)d_in[0];
  const float* stuff_logit = (const float*)d_in[1];
  const float* thing_logit = (const float*)d_in[2];
  const float* bbox        = (const float*)d_in[3];
  const int*   cls_idx     = (const int*)d_in[4];
  const int*   gt          = (const int*)d_in[5];
  float* out = (float*)d_out;

  dim3 grid(GX_, G_);
  fused_kernel<<<grid, BT_, 0, stream>>>(mask_logits, stuff_logit, thing_logit,
                                         bbox, cls_idx, gt, out);
}

// Round 8
// 225.157 us; speedup vs baseline: 1.4701x; 1.4701x over previous
//
#include <hip/hip_runtime.h>
#include <math.h>

#define N_   128
#define H_   400
#define W_   400
#define MS_  28
#define CT_  80
#define CS_  53
#define HW_  (H_*W_)
#define NCH_ (CS_ + N_)   // 181
#define WG_  1600
#define IGN_ 255
#define G_   8            // channel groups
#define CPG_ 23           // ceil(181/8)
#define PPT_ 4            // pixels per thread (float4)
#define BT_  256          // threads per block
#define PPB_ (BT_*PPT_)   // 1024 pixels per block
#define GX_  ((HW_ + PPB_ - 1)/PPB_)   // 157

struct NParam {
  int vy_lo, vy_hi, vx_lo, vx_hi;   // mask-valid box (inclusive)
  int cy1, cy2, cx1, cx2;           // sem box (y in [cy1,cy2), x in [cx1,cx2))
  float sy, sx;                     // 28/hh, 28/ww
  int y0b, x0b;                     // floor(bbox/4)
  int mlbase, thbase;               // offsets into mask_logits / thing_logit
  int pad0, pad1;                   // 64 B
};

// Device globals (no d_ws use). main_kernel re-zeroes g_acc/g_done each
// launch (stream-ordered before reduce_kernel) -> graph-replay safe.
__device__ float        g_acc[2];
__device__ unsigned int g_done;
__device__ float        g_lp[G_*HW_];   // per-(group,pixel) partial LSE: m+log(s)
__device__ float        g_vt[HW_];      // target-channel logit per pixel

__device__ __forceinline__ void lse_update(float v, float& m, float& s) {
  float d = v - m;
  float e = __expf(-fabsf(d));
  s = (d > 0.0f) ? fmaf(s, e, 1.0f) : (s + e);
  m = fmaxf(m, v);
}

// Phase 1: blockIdx.x = pixel tile (4 px/thread), blockIdx.y = channel group.
__global__ __launch_bounds__(256) void main_kernel(
    const float* __restrict__ mask_logits,
    const float* __restrict__ stuff_logit,
    const float* __restrict__ thing_logit,
    const float* __restrict__ bbox,
    const int*   __restrict__ cls_idx,
    const int*   __restrict__ gt,
    float* __restrict__ out)
{
  __shared__ NParam spar[N_];
  int tid = threadIdx.x;
  if (blockIdx.x == 0 && blockIdx.y == 0 && tid == 0) {
    g_acc[0] = 0.0f; g_acc[1] = 0.0f; g_done = 0u;
  }
  if (tid < N_) {
    int n = tid;
    float b0 = bbox[4*n+0]*0.25f, b1 = bbox[4*n+1]*0.25f,
          b2 = bbox[4*n+2]*0.25f, b3 = bbox[4*n+3]*0.25f;
    int x0b = (int)floorf(b0), y0b = (int)floorf(b1);
    int x2b = (int)floorf(b2), y2b = (int)floorf(b3);
    int hh = y2b - y0b + 1, ww = x2b - x0b + 1;
    NParam p;
    p.vy_lo = max(y0b, 0); p.vy_hi = min(y2b, H_-1);
    p.vx_lo = max(x0b, 0); p.vx_hi = min(x2b, W_-1);
    p.cy1 = (int)b1; p.cx1 = (int)b0;                 // trunc (positive)
    p.cy2 = (int)(rintf(b3) + 1.0f);                  // jnp.round = RNE
    p.cx2 = (int)(rintf(b2) + 1.0f);
    p.sy = 28.0f / (float)hh; p.sx = 28.0f / (float)ww;
    p.y0b = y0b; p.x0b = x0b;
    int cls = cls_idx[n];
    p.mlbase = (n*CT_ + cls)*(MS_*MS_);
    p.thbase = cls*HW_;
    p.pad0 = 0; p.pad1 = 0;
    spar[n] = p;
  }
  __syncthreads();

  int pix0 = (blockIdx.x*BT_ + tid)*PPT_;
  if (pix0 >= HW_) return;
  int y  = pix0 / W_;            // W_ % 4 == 0: all 4 pixels share y
  int xb = pix0 - y*W_;

  int grp = blockIdx.y;
  int c0 = grp*CPG_;
  int c1 = min(NCH_, c0 + CPG_);

  // target channel per pixel (gt line is LLC-hot across the 8 groups)
  int tcs[PPT_];
  #pragma unroll
  for (int k = 0; k < PPT_; ++k) {
    int g = gt[y*(4*WG_) + (xb + k)*4];
    tcs[k] = min(max(g, 0), NCH_-1);
  }

  float mv[PPT_], sv[PPT_], vts[PPT_];
  #pragma unroll
  for (int k = 0; k < PPT_; ++k) { mv[k] = -INFINITY; sv[k] = 0.0f; vts[k] = 0.0f; }

  int c = c0;
  // ---- stuff channels in this group: float4 copy + lse ----
  for (; c < min(c1, CS_); ++c) {
    float4 v = *(const float4*)(stuff_logit + c*HW_ + pix0);
    *(float4*)(out + c*HW_ + pix0) = v;
    float vk[4] = {v.x, v.y, v.z, v.w};
    #pragma unroll
    for (int k = 0; k < PPT_; ++k) {
      lse_update(vk[k], mv[k], sv[k]);
      if (c == tcs[k]) vts[k] = vk[k];
    }
  }
  // ---- thing channels in this group ----
  for (; c < c1; ++c) {
    int n = c - CS_;
    NParam p = spar[n];
    float vv[PPT_] = {0.0f, 0.0f, 0.0f, 0.0f};
    if (y >= p.cy1 && y < p.cy2 && xb < p.cx2 && xb+PPT_-1 >= p.cx1) {
      float4 t = *(const float4*)(thing_logit + p.thbase + pix0);
      float tk[4] = {t.x, t.y, t.z, t.w};
      #pragma unroll
      for (int k = 0; k < PPT_; ++k) {
        int x = xb + k;
        if (x >= p.cx1 && x < p.cx2) vv[k] = tk[k];
      }
    }
    if (y >= p.vy_lo && y <= p.vy_hi && xb <= p.vx_hi && xb+PPT_-1 >= p.vx_lo) {
      float srcy = ((float)(y - p.y0b) + 0.5f)*p.sy - 0.5f;
      float fy = floorf(srcy); float ty = srcy - fy;
      int i0 = (int)fminf(fmaxf(fy,        0.0f), (float)(MS_-1));
      int i1 = (int)fminf(fmaxf(fy + 1.0f, 0.0f), (float)(MS_-1));
      const float* r0p = mask_logits + p.mlbase + i0*MS_;
      const float* r1p = mask_logits + p.mlbase + i1*MS_;
      #pragma unroll
      for (int k = 0; k < PPT_; ++k) {
        int x = xb + k;
        if (x >= p.vx_lo && x <= p.vx_hi) {
          float srcx = ((float)(x - p.x0b) + 0.5f)*p.sx - 0.5f;
          float fx = floorf(srcx); float tx = srcx - fx;
          int j0 = (int)fminf(fmaxf(fx,        0.0f), (float)(MS_-1));
          int j1 = (int)fminf(fmaxf(fx + 1.0f, 0.0f), (float)(MS_-1));
          float r0 = r0p[j0]*(1.0f - tx) + r0p[j1]*tx;
          float r1 = r1p[j0]*(1.0f - tx) + r1p[j1]*tx;
          vv[k] += r0*(1.0f - ty) + r1*ty;
        }
      }
    }
    *(float4*)(out + c*HW_ + pix0) = make_float4(vv[0], vv[1], vv[2], vv[3]);
    #pragma unroll
    for (int k = 0; k < PPT_; ++k) {
      lse_update(vv[k], mv[k], sv[k]);
      if (c == tcs[k]) vts[k] = vv[k];
    }
  }

  // compressed partial: lp = m + log(s)  (s >= 1 always)
  float4 lp = make_float4(mv[0] + __logf(sv[0]), mv[1] + __logf(sv[1]),
                          mv[2] + __logf(sv[2]), mv[3] + __logf(sv[3]));
  *(float4*)(g_lp + grp*HW_ + pix0) = lp;

  // exactly one group owns each pixel's target channel
  #pragma unroll
  for (int k = 0; k < PPT_; ++k)
    if (tcs[k] >= c0 && tcs[k] < c1) g_vt[pix0 + k] = vts[k];
}

// Phase 2: combine per-group LSEs, read captured target logit, reduce NLL;
// last block (ticket) writes the loss.
__global__ __launch_bounds__(256) void reduce_kernel(
    const int* __restrict__ gt,
    float* __restrict__ out)
{
  int tid = threadIdx.x;
  int pix0 = (blockIdx.x*BT_ + tid)*PPT_;
  float nll = 0.0f, cnt = 0.0f;
  if (pix0 < HW_) {
    float4 l0 = *(const float4*)(g_lp + pix0);
    float mv[PPT_] = {l0.x, l0.y, l0.z, l0.w};
    float sv[PPT_] = {1.0f, 1.0f, 1.0f, 1.0f};
    #pragma unroll
    for (int g = 1; g < G_; ++g) {
      float4 lg4 = *(const float4*)(g_lp + g*HW_ + pix0);
      float lg[PPT_] = {lg4.x, lg4.y, lg4.z, lg4.w};
      #pragma unroll
      for (int k = 0; k < PPT_; ++k) {
        float d = lg[k] - mv[k];
        float e = __expf(-fabsf(d));
        sv[k] = (d > 0.0f) ? fmaf(sv[k], e, 1.0f) : (sv[k] + e);
        mv[k] = fmaxf(mv[k], lg[k]);
      }
    }
    float4 vt4 = *(const float4*)(g_vt + pix0);
    float vt[PPT_] = {vt4.x, vt4.y, vt4.z, vt4.w};
    int y  = pix0 / W_;
    int xb = pix0 - y*W_;
    #pragma unroll
    for (int k = 0; k < PPT_; ++k) {
      int g = gt[y*(4*WG_) + (xb + k)*4];     // gt_panoptic[4y, 4x]
      bool valid = (g != IGN_);
      nll += valid ? (mv[k] + __logf(sv[k]) - vt[k]) : 0.0f;
      cnt += valid ? 1.0f : 0.0f;
    }
  }

  for (int off = 32; off >= 1; off >>= 1) {
    nll += __shfl_down(nll, off, 64);
    cnt += __shfl_down(cnt, off, 64);
  }
  __shared__ float red[8];
  int lane = tid & 63, wid = tid >> 6;
  if (lane == 0) { red[wid*2] = nll; red[wid*2+1] = cnt; }
  __syncthreads();
  if (tid == 0) {
    float ts  = red[0] + red[2] + red[4] + red[6];
    float tcn = red[1] + red[3] + red[5] + red[7];
    atomicAdd(&g_acc[0], ts);
    atomicAdd(&g_acc[1], tcn);
    __threadfence();
    unsigned int d = atomicAdd(&g_done, 1u);
    if (d == gridDim.x - 1) {
      __threadfence();
      float loss = g_acc[0] / fmaxf(g_acc[1], 1.0f);   // LOSS_W = 1.0
      out[NCH_*HW_] = loss;
    }
  }
}

extern "C" void kernel_launch(void* const* d_in, const int* in_sizes, int n_in,
                              void* d_out, int out_size, void* d_ws, size_t ws_size,
                              hipStream_t stream) {
  const float* mask_logits = (const float*)d_in[0];
  const float* stuff_logit = (const float*)d_in[1];
  const float* thing_logit = (const float*)d_in[2];
  const float* bbox        = (const float*)d_in[3];
  const int*   cls_idx     = (const int*)d_in[4];
  const int*   gt          = (const int*)d_in[5];
  float* out = (float*)d_out;

  dim3 grid1(GX_, G_);
  main_kernel<<<grid1, BT_, 0, stream>>>(mask_logits, stuff_logit, thing_logit,
                                         bbox, cls_idx, gt, out);
  reduce_kernel<<<GX_, BT_, 0, stream>>>(gt, out);
}